// Round 21
// baseline (96.985 us; speedup 1.0000x reference)
//
#include <hip/hip_runtime.h>

#define L_ 9216

typedef unsigned int uint;
typedef unsigned short ushort;
typedef __attribute__((ext_vector_type(8))) short short8;
typedef __attribute__((ext_vector_type(4))) float f32x4;
typedef __attribute__((ext_vector_type(16))) float f32x16;
typedef __attribute__((ext_vector_type(4))) unsigned uint4v;
typedef __attribute__((ext_vector_type(2))) unsigned uint2v;

#define MFMA32(a, b, c) __builtin_amdgcn_mfma_f32_32x32x16_bf16(a, b, c, 0, 0, 0)

#if __has_builtin(__builtin_amdgcn_exp2f)
#define EXP2(x) __builtin_amdgcn_exp2f(x)
#else
#define EXP2(x) exp2f(x)
#endif

union B8 {
  uint4v u;
  short8 s;
};

__device__ __forceinline__ ushort f2bf(float f) {
  uint u = __float_as_uint(f);
  return (ushort)((u + 0x7fffu + ((u >> 16) & 1u)) >> 16);
}

__device__ __forceinline__ f32x16 zero16() {
  f32x16 v;
#pragma unroll
  for (int i = 0; i < 16; i++) v[i] = 0.f;
  return v;
}

// ---------------- MFMA projection (W converted f32->bf16 inline) --------
// One wave per block; 32 positions x 64 outs, full CC channels.
// C[out][pos] = W * X; col = pos = lane&31, row = (r&3)+8*(r>>2)+4*hs.
// TASK 0=Q ([pos][64], l2norm, xlog2e), 1=K (FRAGMENT-MAJOR, l2norm),
// 2=V (FRAGMENT-MAJOR).
// Kf layout: [b][j][st][m][lane][8]: elem = K[j*64+st*32+(l&31)][m*16+(l>>5)*8+i]
// Vf layout: [b][j][dt][s][lane][8]: elem = V[dt*32+(l&31)][j*64+s*16+(l>>5)*8+i]
template <int CC, int TASK>
__device__ __forceinline__ void projm_body(
    const float* __restrict__ X,     // [2][CC][L]
    const float* __restrict__ Wf,    // [64][CC] f32
    const float* __restrict__ bias,  // [64]
    ushort* __restrict__ dst) {
  constexpr int NKT = CC / 16;
  const int bx = blockIdx.x;  // 0..575
  const int b = bx / 288;
  const int p0 = (bx - b * 288) * 32;
  const int lane = threadIdx.x;
  const int ql = lane & 31;
  const int hs = lane >> 5;

  // X loads: B-frag needs X[ch = kt*16 + hs*8 + i][p0 + ql]
  const float* Xb = X + (size_t)b * CC * L_ + p0 + ql;
  float xv[NKT * 8];
#pragma unroll
  for (int kt = 0; kt < NKT; kt++)
#pragma unroll
    for (int i = 0; i < 8; i++)
      xv[kt * 8 + i] = Xb[(size_t)(kt * 16 + hs * 8 + i) * L_];

  // pack X to bf16 B-frags
  B8 bfr[NKT];
#pragma unroll
  for (int kt = 0; kt < NKT; kt++)
#pragma unroll
    for (int j = 0; j < 4; j++) {
      uint lo = f2bf(xv[kt * 8 + 2 * j]);
      uint hi = f2bf(xv[kt * 8 + 2 * j + 1]);
      bfr[kt].u[j] = lo | (hi << 16);
    }

  // A-frags from f32 W (L2-resident), converted inline to bf16
  const float* Wr0 = Wf + (size_t)ql * CC + hs * 8;
  const float* Wr1 = Wf + (size_t)(32 + ql) * CC + hs * 8;

  f32x16 a0 = zero16(), a1 = zero16();
#pragma unroll
  for (int kt = 0; kt < NKT; kt++) {
    float4 wa0 = *(const float4*)(Wr0 + kt * 16);
    float4 wb0 = *(const float4*)(Wr0 + kt * 16 + 4);
    float4 wa1 = *(const float4*)(Wr1 + kt * 16);
    float4 wb1 = *(const float4*)(Wr1 + kt * 16 + 4);
    B8 w0, w1;
    w0.u[0] = (uint)f2bf(wa0.x) | ((uint)f2bf(wa0.y) << 16);
    w0.u[1] = (uint)f2bf(wa0.z) | ((uint)f2bf(wa0.w) << 16);
    w0.u[2] = (uint)f2bf(wb0.x) | ((uint)f2bf(wb0.y) << 16);
    w0.u[3] = (uint)f2bf(wb0.z) | ((uint)f2bf(wb0.w) << 16);
    w1.u[0] = (uint)f2bf(wa1.x) | ((uint)f2bf(wa1.y) << 16);
    w1.u[1] = (uint)f2bf(wa1.z) | ((uint)f2bf(wa1.w) << 16);
    w1.u[2] = (uint)f2bf(wb1.x) | ((uint)f2bf(wb1.y) << 16);
    w1.u[3] = (uint)f2bf(wb1.z) | ((uint)f2bf(wb1.w) << 16);
    a0 = MFMA32(w0.s, bfr[kt].s, a0);
    a1 = MFMA32(w1.s, bfr[kt].s, a1);
  }

  // + bias: reg r -> out = mt*32 + (r&3) + 8*(r>>2) + 4*hs
#pragma unroll
  for (int g = 0; g < 4; g++) {
    float4 b0 = *(const float4*)(bias + 8 * g + 4 * hs);
    float4 b1 = *(const float4*)(bias + 32 + 8 * g + 4 * hs);
    a0[4 * g + 0] += b0.x; a0[4 * g + 1] += b0.y;
    a0[4 * g + 2] += b0.z; a0[4 * g + 3] += b0.w;
    a1[4 * g + 0] += b1.x; a1[4 * g + 1] += b1.y;
    a1[4 * g + 2] += b1.z; a1[4 * g + 3] += b1.w;
  }

  if (TASK < 2) {
    float ss = 0.f;
#pragma unroll
    for (int r = 0; r < 16; r++) ss += a0[r] * a0[r] + a1[r] * a1[r];
    ss += __shfl_xor(ss, 32);  // other hs half's rows, same pos
    float i0 = 1.0f / fmaxf(sqrtf(ss), 1e-6f);
    if (TASK == 0) {
      // Q: [pos][64] layout, log2e folded
      i0 *= 1.44269504f;
      uint* d = (uint*)(dst + ((size_t)(b * L_ + p0 + ql)) * 64);
#pragma unroll
      for (int g = 0; g < 4; g++) {
        uint2v u0, u1;
        u0[0] = (uint)f2bf(a0[4 * g + 0] * i0) | ((uint)f2bf(a0[4 * g + 1] * i0) << 16);
        u0[1] = (uint)f2bf(a0[4 * g + 2] * i0) | ((uint)f2bf(a0[4 * g + 3] * i0) << 16);
        u1[0] = (uint)f2bf(a1[4 * g + 0] * i0) | ((uint)f2bf(a1[4 * g + 1] * i0) << 16);
        u1[1] = (uint)f2bf(a1[4 * g + 2] * i0) | ((uint)f2bf(a1[4 * g + 3] * i0) << 16);
        *(uint2v*)(d + 4 * g + 2 * hs) = u0;
        *(uint2v*)(d + 16 + 4 * g + 2 * hs) = u1;
      }
    } else {
      // K: fragment-major. This block's 32 positions are one (j, st) slice.
      // dims d0..d0+3 (per mt,rq) -> frag (m = mt*2+(rq>>1)), lane
      // lp = ql + 32*(rq&1), elems i = 4*hs..+3.
      const int j = p0 >> 6;
      const int st = (p0 >> 5) & 1;
      ushort* Kfb = dst + (size_t)b * L_ * 64;
#pragma unroll
      for (int mt = 0; mt < 2; mt++) {
#pragma unroll
        for (int rq = 0; rq < 4; rq++) {
          const float* x = mt ? (const float*)&a1 : (const float*)&a0;
          int m = mt * 2 + (rq >> 1);
          int lp = ql + 32 * (rq & 1);
          uint2v v;
          v[0] = (uint)f2bf(x[rq * 4 + 0] * i0) |
                 ((uint)f2bf(x[rq * 4 + 1] * i0) << 16);
          v[1] = (uint)f2bf(x[rq * 4 + 2] * i0) |
                 ((uint)f2bf(x[rq * 4 + 3] * i0) << 16);
          *(uint2v*)(Kfb + (size_t)(j * 8 + st * 4 + m) * 512 + lp * 8 +
                     4 * hs) = v;
        }
      }
    }
  } else {
    // V: fragment-major. Thread's position pos = p0+ql fixes (s,hkv,i);
    // each out dv -> lane lp = (dv&31) + 32*hkv, frag (dt=mt, s).
    const int j = p0 >> 6;
    const int kvo = (p0 & 63) + ql;
    const int s = kvo >> 4;
    const int hkv = (kvo >> 3) & 1;
    const int i = kvo & 7;
    ushort* Vfb = dst + (size_t)b * L_ * 64;
#pragma unroll
    for (int mt = 0; mt < 2; mt++) {
      const float* x = mt ? (const float*)&a1 : (const float*)&a0;
#pragma unroll
      for (int r = 0; r < 16; r++) {
        int dvl = (r & 3) + 8 * (r >> 2) + 4 * hs;  // dv & 31
        int lp = dvl + 32 * hkv;
        Vfb[(size_t)(j * 8 + mt * 4 + s) * 512 + lp * 8 + i] = f2bf(x[r]);
      }
    }
  }
}

__global__ __launch_bounds__(64) void projm_kernel(
    const float* __restrict__ x, const float* __restrict__ x_enc,
    const float* __restrict__ Wq, const float* __restrict__ bq,
    const float* __restrict__ Wk, const float* __restrict__ bk,
    const float* __restrict__ Wv, const float* __restrict__ bv,
    ushort* __restrict__ Qb, ushort* __restrict__ Kf,
    ushort* __restrict__ Vf) {
  const int task = blockIdx.y;
  if (task == 0)
    projm_body<96, 0>(x_enc, Wq, bq, Qb);
  else if (task == 1)
    projm_body<96, 1>(x_enc, Wk, bk, Kf);
  else
    projm_body<64, 2>(x, Wv, bv, Vf);
}

// ---------------- flash attention, KV-split, NO LDS / NO barriers -------
// grid = 72*SPLIT blocks, 512 thr = 8 waves x 32 q-rows (256 q/block).
// K/V in FRAGMENT-MAJOR global layout: every fragment load is wave-uniform
// base + lane*16B -> one coalesced 1KB transaction, L1-resident (16KB/tile).
// No LDS, no barriers, no waitcnt drains -> waves fully independent; MFMA,
// VALU and VMEM overlap across waves instead of summing (r18's diagnosis).
// Arithmetic identical to r18 (zv zero-C, SMPK, PVH interleave, denom-MFMA).
// Qb (log2e-scaled): [b][pos][64]. Kf/Vf: fragment-major (see projm).
// OP: [split][b][dv][L] bf16 unnormalized. LB: [split][b][L] fp32 denoms.
__global__ __launch_bounds__(512) void attn_kernel(
    const ushort* __restrict__ Qb, const ushort* __restrict__ Kf,
    const ushort* __restrict__ Vf, ushort* __restrict__ OP,
    float* __restrict__ LB, int tps) {
  const int nwg = gridDim.x;
  const int chunk = nwg >> 3;  // nwg = 72*SPLIT, always % 8 == 0
  const int bid = blockIdx.x;
  const int logical = (bid & 7) * chunk + (bid >> 3);
  const int split = logical / 72;
  const int qidx = logical - split * 72;
  const int b = qidx / 36;
  const int q0 = (qidx - b * 36) * 256;

  const int t = threadIdx.x;
  const int lane = t & 63;
  const int w = t >> 6;  // 0..7
  const int ql = lane & 31;
  const int hs = lane >> 5;

  // Q fragments: B-operand, col(q) = lane&31, k = hs*8+i per 16-chunk
  const int qrow = q0 + w * 32 + ql;
  const ushort* Qr = Qb + ((size_t)(b * L_ + qrow)) * 64 + hs * 8;
  short8 qf[4];
  qf[0] = *(const short8*)(Qr);
  qf[1] = *(const short8*)(Qr + 16);
  qf[2] = *(const short8*)(Qr + 32);
  qf[3] = *(const short8*)(Qr + 48);

  // ones A-fragment (bf16 1.0) for the denominator MFMA
  B8 onesu;
  onesu.u[0] = 0x3F803F80u;
  onesu.u[1] = 0x3F803F80u;
  onesu.u[2] = 0x3F803F80u;
  onesu.u[3] = 0x3F803F80u;

  f32x16 o[2];
  o[0] = zero16();
  o[1] = zero16();
  f32x16 od = zero16();  // denominator accumulator (all rows identical)
  f32x16 zv = zero16();  // persistent zero C-operand (never written again)

  // per-lane fragment element offset (lane*8 elems = lane*16B)
  const int le = lane * 8;
  const ushort* Kb0 = Kf + (size_t)b * L_ * 64 + le;
  const ushort* Vb0 = Vf + (size_t)b * L_ * 64 + le;
  const int jb = split * tps;  // first tile of this split

  // softmax+pack one st slice into pf[st*2], pf[st*2+1]: exp2,
  // truncate-pack via v_perm, redistribute hs halves via permlane32_swap
  // (dst-hi <-> src-lo).
#define SMPK1(sa, pf, st)                                                  \
  {                                                                        \
    uint Wp[8];                                                            \
    _Pragma("unroll") for (int c = 0; c < 4; c++) _Pragma("unroll")        \
        for (int rp = 0; rp < 2; rp++) {                                   \
      int i0 = 4 * c + 2 * rp;                                             \
      float p0 = EXP2(sa[i0]);                                             \
      float p1 = EXP2(sa[i0 + 1]);                                         \
      Wp[2 * c + rp] = __builtin_amdgcn_perm(__float_as_uint(p1),          \
                                             __float_as_uint(p0),          \
                                             0x07060302u);                 \
    }                                                                      \
    _Pragma("unroll") for (int u = 0; u < 2; u++) {                        \
      auto ra = __builtin_amdgcn_permlane32_swap(Wp[4 * u + 0],            \
                                                 Wp[4 * u + 2], false,     \
                                                 false);                   \
      auto rb = __builtin_amdgcn_permlane32_swap(Wp[4 * u + 1],            \
                                                 Wp[4 * u + 3], false,     \
                                                 false);                   \
      uint4v fw;                                                           \
      fw[0] = ra[0];                                                       \
      fw[1] = rb[0];                                                       \
      fw[2] = ra[1];                                                       \
      fw[3] = rb[1];                                                       \
      pf[(st)*2 + u].u = fw;                                               \
    }                                                                      \
  }

  for (int tt = 0; tt < tps; tt++) {
    const size_t jo = (size_t)((jb + tt) * 8) * 512;
    const ushort* Kt = Kb0 + jo;  // frags (st*4+m)*512
    const ushort* Vt = Vb0 + jo;  // frags (dt*4+s)*512

    // K fragment loads (coalesced 1KB each, L1-resident)
    short8 kf0[4], kf1[4];
#pragma unroll
    for (int m = 0; m < 4; m++) {
      kf0[m] = *(const short8*)(Kt + m * 512);
      kf1[m] = *(const short8*)(Kt + (4 + m) * 512);
    }

    // QK both st slices; first MFMA of each chain uses zv as C (D != C)
    f32x16 s0, s1;
    __builtin_amdgcn_s_setprio(1);
    s0 = MFMA32(kf0[0], qf[0], zv);
    s1 = MFMA32(kf1[0], qf[0], zv);
#pragma unroll
    for (int m = 1; m < 4; m++) {
      s0 = MFMA32(kf0[m], qf[m], s0);
      s1 = MFMA32(kf1[m], qf[m], s1);
    }
    __builtin_amdgcn_s_setprio(0);

    // V fragment loads (latency hidden under SMPK VALU)
    short8 vf0[4], vf1[4];
#pragma unroll
    for (int s = 0; s < 4; s++) {
      vf0[s] = *(const short8*)(Vt + s * 512);
      vf1[s] = *(const short8*)(Vt + (4 + s) * 512);
    }

    B8 pf[4];
    SMPK1(s0, pf, 0);
    SMPK1(s1, pf, 1);

    __builtin_amdgcn_s_setprio(1);
#pragma unroll
    for (int s = 0; s < 4; s++) od = MFMA32(onesu.s, pf[s].s, od);
#pragma unroll
    for (int s = 0; s < 4; s++) {
      o[0] = MFMA32(vf0[s], pf[s].s, o[0]);
      o[1] = MFMA32(vf1[s], pf[s].s, o[1]);
    }
    __builtin_amdgcn_s_setprio(0);
  }

  // epilogue: denom = od[0] (all rows identical; row 0 lives in hs==0's r=0)
  if (hs == 0) LB[(size_t)split * 2 * L_ + (size_t)b * L_ + qrow] = od[0];

  ushort* Ob = OP + (size_t)split * 2 * 64 * L_;
#pragma unroll
  for (int dt = 0; dt < 2; dt++)
#pragma unroll
    for (int r = 0; r < 16; r++) {
      int dv = dt * 32 + (r & 3) + 8 * (r >> 2) + 4 * hs;
      Ob[(size_t)(b * 64 + dv) * L_ + qrow] = f2bf(o[dt][r]);
    }
}

// ---------------- combine splits (unrolled over NS) ----------------
// 8 output elements per thread. OP bf16, LB fp32.
template <int NS>
__global__ __launch_bounds__(256) void combine_kernel(
    const ushort* __restrict__ OP, const float* __restrict__ LB,
    float* __restrict__ out) {
  const size_t e = ((size_t)blockIdx.x * 256 + threadIdx.x) * 8;
  const int bdv = (int)(e / L_);
  const int b = bdv >> 6;
  const int q = (int)(e % L_);
  float os[8], ls[8];
#pragma unroll
  for (int i = 0; i < 8; i++) { os[i] = 0.f; ls[i] = 0.f; }
#pragma unroll
  for (int s = 0; s < NS; s++) {
    uint4v pv = *(const uint4v*)(OP + (size_t)s * 2 * 64 * L_ + e);
    const float* lp = LB + (size_t)s * 2 * L_ + (size_t)b * L_ + q;
    f32x4 l0 = *(const f32x4*)(lp);
    f32x4 l1 = *(const f32x4*)(lp + 4);
#pragma unroll
    for (int i = 0; i < 4; i++) {
      os[2 * i] += __uint_as_float(pv[i] << 16);
      os[2 * i + 1] += __uint_as_float(pv[i] & 0xFFFF0000u);
      ls[i] += l0[i];
      ls[4 + i] += l1[i];
    }
  }
  float r[8];
#pragma unroll
  for (int i = 0; i < 8; i++) r[i] = os[i] / ls[i];
  *(f32x4*)(out + e) = *(const f32x4*)&r[0];
  *(f32x4*)(out + e + 4) = *(const f32x4*)&r[4];
}

extern "C" void kernel_launch(void* const* d_in, const int* in_sizes, int n_in,
                              void* d_out, int out_size, void* d_ws, size_t ws_size,
                              hipStream_t stream) {
  const float* x = (const float*)d_in[0];
  const float* x_enc = (const float*)d_in[1];
  const float* Wq = (const float*)d_in[2];
  const float* bq = (const float*)d_in[3];
  const float* Wk = (const float*)d_in[4];
  const float* bk = (const float*)d_in[5];
  const float* Wv = (const float*)d_in[6];
  const float* bv = (const float*)d_in[7];
  float* out = (float*)d_out;

  ushort* Qb = (ushort*)d_ws;
  ushort* Kf = Qb + (size_t)2 * L_ * 64;
  ushort* Vf = Kf + (size_t)2 * L_ * 64;
  const size_t qkv_bytes = (size_t)3 * 2 * L_ * 64 * 2;  // 7,077,888

  // SPLIT = 16 fixed (ws fit confirmed rounds 11-20: OP bf16 ~37.7MB + LB)
  const int SPLIT = 16;
  ushort* OP = (ushort*)((char*)d_ws + qkv_bytes);
  float* LB = (float*)(OP + (size_t)SPLIT * 2 * 64 * L_);

  projm_kernel<<<dim3(576, 3), 64, 0, stream>>>(x, x_enc, Wq, bq, Wk, bk,
                                                Wv, bv, Qb, Kf, Vf);
  attn_kernel<<<72 * SPLIT, 512, 0, stream>>>(Qb, Kf, Vf, OP, LB, 144 / SPLIT);
  const int cgrid = (2 * 64 * L_ / 8) / 256;
  combine_kernel<16><<<cgrid, 256, 0, stream>>>(OP, LB, out);
}

// Round 22
// 81.379 us; speedup vs baseline: 1.1918x; 1.1918x over previous
//
#include <hip/hip_runtime.h>

#define L_ 9216

typedef unsigned int uint;
typedef unsigned short ushort;
typedef __attribute__((ext_vector_type(8))) short short8;
typedef __attribute__((ext_vector_type(4))) float f32x4;
typedef __attribute__((ext_vector_type(16))) float f32x16;
typedef __attribute__((ext_vector_type(4))) unsigned uint4v;
typedef __attribute__((ext_vector_type(2))) unsigned uint2v;

#define MFMA32(a, b, c) __builtin_amdgcn_mfma_f32_32x32x16_bf16(a, b, c, 0, 0, 0)

#if __has_builtin(__builtin_amdgcn_exp2f)
#define EXP2(x) __builtin_amdgcn_exp2f(x)
#else
#define EXP2(x) exp2f(x)
#endif

#define GLOAD_LDS16(g, l)                                            \
  __builtin_amdgcn_global_load_lds(                                  \
      (const __attribute__((address_space(1))) unsigned int*)(g),    \
      (__attribute__((address_space(3))) unsigned int*)(l), 16, 0, 0)

union B8 {
  uint4v u;
  short8 s;
};

__device__ __forceinline__ ushort f2bf(float f) {
  uint u = __float_as_uint(f);
  return (ushort)((u + 0x7fffu + ((u >> 16) & 1u)) >> 16);
}

__device__ __forceinline__ f32x16 zero16() {
  f32x16 v;
#pragma unroll
  for (int i = 0; i < 16; i++) v[i] = 0.f;
  return v;
}

// ---------------- MFMA projection (W converted f32->bf16 inline) --------
// One wave per block; 32 positions x 64 outs, full CC channels.
// C[out][pos] = W * X; col = pos = lane&31, row = (r&3)+8*(r>>2)+4*hs.
// TASK 0=Q (l2norm, xlog2e), 1=K (l2norm), 2=V (store [dv][pos]).
template <int CC, int TASK>
__device__ __forceinline__ void projm_body(
    const float* __restrict__ X,     // [2][CC][L]
    const float* __restrict__ Wf,    // [64][CC] f32
    const float* __restrict__ bias,  // [64]
    ushort* __restrict__ dst) {      // Q/K: [2][L][64]; V: [2][64][L]
  constexpr int NKT = CC / 16;
  const int bx = blockIdx.x;  // 0..575
  const int b = bx / 288;
  const int p0 = (bx - b * 288) * 32;
  const int lane = threadIdx.x;
  const int ql = lane & 31;
  const int hs = lane >> 5;

  // X loads: B-frag needs X[ch = kt*16 + hs*8 + i][p0 + ql]
  const float* Xb = X + (size_t)b * CC * L_ + p0 + ql;
  float xv[NKT * 8];
#pragma unroll
  for (int kt = 0; kt < NKT; kt++)
#pragma unroll
    for (int i = 0; i < 8; i++)
      xv[kt * 8 + i] = Xb[(size_t)(kt * 16 + hs * 8 + i) * L_];

  // pack X to bf16 B-frags
  B8 bfr[NKT];
#pragma unroll
  for (int kt = 0; kt < NKT; kt++)
#pragma unroll
    for (int j = 0; j < 4; j++) {
      uint lo = f2bf(xv[kt * 8 + 2 * j]);
      uint hi = f2bf(xv[kt * 8 + 2 * j + 1]);
      bfr[kt].u[j] = lo | (hi << 16);
    }

  // A-frags from f32 W (L2-resident, 24KB), converted inline to bf16:
  // row = mt*32 + ql, k = kt*16 + hs*8 + i. Same RTN as a prep pass.
  const float* Wr0 = Wf + (size_t)ql * CC + hs * 8;
  const float* Wr1 = Wf + (size_t)(32 + ql) * CC + hs * 8;

  f32x16 a0 = zero16(), a1 = zero16();
#pragma unroll
  for (int kt = 0; kt < NKT; kt++) {
    float4 wa0 = *(const float4*)(Wr0 + kt * 16);
    float4 wb0 = *(const float4*)(Wr0 + kt * 16 + 4);
    float4 wa1 = *(const float4*)(Wr1 + kt * 16);
    float4 wb1 = *(const float4*)(Wr1 + kt * 16 + 4);
    B8 w0, w1;
    w0.u[0] = (uint)f2bf(wa0.x) | ((uint)f2bf(wa0.y) << 16);
    w0.u[1] = (uint)f2bf(wa0.z) | ((uint)f2bf(wa0.w) << 16);
    w0.u[2] = (uint)f2bf(wb0.x) | ((uint)f2bf(wb0.y) << 16);
    w0.u[3] = (uint)f2bf(wb0.z) | ((uint)f2bf(wb0.w) << 16);
    w1.u[0] = (uint)f2bf(wa1.x) | ((uint)f2bf(wa1.y) << 16);
    w1.u[1] = (uint)f2bf(wa1.z) | ((uint)f2bf(wa1.w) << 16);
    w1.u[2] = (uint)f2bf(wb1.x) | ((uint)f2bf(wb1.y) << 16);
    w1.u[3] = (uint)f2bf(wb1.z) | ((uint)f2bf(wb1.w) << 16);
    a0 = MFMA32(w0.s, bfr[kt].s, a0);
    a1 = MFMA32(w1.s, bfr[kt].s, a1);
  }

  // + bias: reg r -> out = mt*32 + (r&3) + 8*(r>>2) + 4*hs
#pragma unroll
  for (int g = 0; g < 4; g++) {
    float4 b0 = *(const float4*)(bias + 8 * g + 4 * hs);
    float4 b1 = *(const float4*)(bias + 32 + 8 * g + 4 * hs);
    a0[4 * g + 0] += b0.x; a0[4 * g + 1] += b0.y;
    a0[4 * g + 2] += b0.z; a0[4 * g + 3] += b0.w;
    a1[4 * g + 0] += b1.x; a1[4 * g + 1] += b1.y;
    a1[4 * g + 2] += b1.z; a1[4 * g + 3] += b1.w;
  }

  if (TASK < 2) {
    float ss = 0.f;
#pragma unroll
    for (int r = 0; r < 16; r++) ss += a0[r] * a0[r] + a1[r] * a1[r];
    ss += __shfl_xor(ss, 32);  // other hs half's rows, same pos
    float i0 = 1.0f / fmaxf(sqrtf(ss), 1e-6f);
    if (TASK == 0) i0 *= 1.44269504f;  // fold log2e into Q
    uint* d = (uint*)(dst + ((size_t)(b * L_ + p0 + ql)) * 64);
#pragma unroll
    for (int g = 0; g < 4; g++) {
      uint2v u0, u1;
      u0[0] = (uint)f2bf(a0[4 * g + 0] * i0) | ((uint)f2bf(a0[4 * g + 1] * i0) << 16);
      u0[1] = (uint)f2bf(a0[4 * g + 2] * i0) | ((uint)f2bf(a0[4 * g + 3] * i0) << 16);
      u1[0] = (uint)f2bf(a1[4 * g + 0] * i0) | ((uint)f2bf(a1[4 * g + 1] * i0) << 16);
      u1[1] = (uint)f2bf(a1[4 * g + 2] * i0) | ((uint)f2bf(a1[4 * g + 3] * i0) << 16);
      *(uint2v*)(d + 4 * g + 2 * hs) = u0;        // outs 8g+4hs .. +3
      *(uint2v*)(d + 16 + 4 * g + 2 * hs) = u1;   // outs 32+8g+4hs .. +3
    }
  } else {
    // V: store transposed [dv][pos]; reg r across lanes = one row
#pragma unroll
    for (int r = 0; r < 16; r++) {
      int dv0 = (r & 3) + 8 * (r >> 2) + 4 * hs;
      dst[(size_t)(b * 64 + dv0) * L_ + p0 + ql] = f2bf(a0[r]);
      dst[(size_t)(b * 64 + 32 + dv0) * L_ + p0 + ql] = f2bf(a1[r]);
    }
  }
}

__global__ __launch_bounds__(64) void projm_kernel(
    const float* __restrict__ x, const float* __restrict__ x_enc,
    const float* __restrict__ Wq, const float* __restrict__ bq,
    const float* __restrict__ Wk, const float* __restrict__ bk,
    const float* __restrict__ Wv, const float* __restrict__ bv,
    ushort* __restrict__ Qb, ushort* __restrict__ Kb,
    ushort* __restrict__ Vb) {
  const int task = blockIdx.y;
  if (task == 0)
    projm_body<96, 0>(x_enc, Wq, bq, Qb);
  else if (task == 1)
    projm_body<96, 1>(x_enc, Wk, bk, Kb);
  else
    projm_body<64, 2>(x, Wv, bv, Vb);
}

// ---------------- flash attention, KV-split (best verified body) --------
// grid = 72*SPLIT blocks, 512 thr = 8 waves x 32 q-rows (256 q/block).
// 3-buffer LDS, 2-deep prefetch, counted vmcnt, static addressing,
// zv zero-C trick, PV-halves interleaved with SMPK VALU stretches.
// Qb (log2e-scaled),Kb: [b][pos][64] bf16. Vb: [b][dv][pos] bf16.
// OP: [split][b][dv][L] bf16 unnormalized. LB: [split][b][L] fp32 denoms.
__global__ __launch_bounds__(512, 4) void attn_kernel(
    const ushort* __restrict__ Qb, const ushort* __restrict__ Kb,
    const ushort* __restrict__ Vb, ushort* __restrict__ OP,
    float* __restrict__ LB, int tps) {
  // [buf][0]=K tile [kv][d] swizzled; [buf][1]=V tile [dv][kv] swizzled
  __shared__ __align__(16) ushort KV_l[3][2][4096];

  const int nwg = gridDim.x;
  const int chunk = nwg >> 3;  // nwg = 72*SPLIT, always % 8 == 0
  const int bid = blockIdx.x;
  const int logical = (bid & 7) * chunk + (bid >> 3);
  const int split = logical / 72;
  const int qidx = logical - split * 72;
  const int b = qidx / 36;
  const int q0 = (qidx - b * 36) * 256;

  const int t = threadIdx.x;
  const int lane = t & 63;
  const int w = t >> 6;  // 0..7
  const int ql = lane & 31;
  const int hs = lane >> 5;

  const ushort* Kg = Kb + (size_t)b * L_ * 64;
  const ushort* Vg = Vb + (size_t)b * 64 * L_;

  // Q fragments: B-operand, col(q) = lane&31, k = hs*8+i per 16-chunk
  const int qrow = q0 + w * 32 + ql;
  const ushort* Qr = Qb + ((size_t)(b * L_ + qrow)) * 64 + hs * 8;
  short8 qf[4];
  qf[0] = *(const short8*)(Qr);
  qf[1] = *(const short8*)(Qr + 16);
  qf[2] = *(const short8*)(Qr + 32);
  qf[3] = *(const short8*)(Qr + 48);

  // ones A-fragment (bf16 1.0) for the denominator MFMA
  B8 onesu;
  onesu.u[0] = 0x3F803F80u;
  onesu.u[1] = 0x3F803F80u;
  onesu.u[2] = 0x3F803F80u;
  onesu.u[3] = 0x3F803F80u;

  f32x16 o[2];
  o[0] = zero16();
  o[1] = zero16();
  f32x16 od = zero16();  // denominator accumulator (all rows identical)
  f32x16 zv = zero16();  // persistent zero C-operand (never written again)

  // hoisted LDS read byte-addresses: frag at
  //   arf[m] + buf*16384 + {K:0|V:8192} + {st|dt}*4096  (imm <= 53232)
  const int ksw = (ql & 7) << 3;
  const char* lds0 = (const char*)&KV_l[0][0][0];
  int arf[4];
#pragma unroll
  for (int m = 0; m < 4; m++)
    arf[m] = (ql * 64 + ((m * 16 + hs * 8) ^ ksw)) * 2;

  // staging: 512 threads cover 512 chunks of 16B per 8KB tile -> 1 K-load +
  // 1 V-load per thread. LDS linear (wave base + lane*16B), global source
  // pre-swizzled (inverse of the read-side XOR).
  const int rr = t >> 3, pl = t & 7;
  const int psrc = (pl ^ (rr & 7)) << 3;
  const int j0base = split * tps * 64;

#define STAGE(buf, j0)                                                     \
  {                                                                        \
    GLOAD_LDS16(Kg + (size_t)(j0)*64 + rr * 64 + psrc,                     \
                &KV_l[buf][0][w * 512]);                                   \
    GLOAD_LDS16(Vg + (size_t)rr * L_ + (j0) + psrc,                        \
                &KV_l[buf][1][w * 512]);                                   \
  }

  // softmax+pack one st slice into pf[st*2], pf[st*2+1]: exp2,
  // truncate-pack via v_perm, redistribute hs halves via permlane32_swap
  // (dst-hi <-> src-lo).
#define SMPK1(sa, pf, st)                                                  \
  {                                                                        \
    uint Wp[8];                                                            \
    _Pragma("unroll") for (int c = 0; c < 4; c++) _Pragma("unroll")        \
        for (int rp = 0; rp < 2; rp++) {                                   \
      int i0 = 4 * c + 2 * rp;                                             \
      float p0 = EXP2(sa[i0]);                                             \
      float p1 = EXP2(sa[i0 + 1]);                                         \
      Wp[2 * c + rp] = __builtin_amdgcn_perm(__float_as_uint(p1),          \
                                             __float_as_uint(p0),          \
                                             0x07060302u);                 \
    }                                                                      \
    _Pragma("unroll") for (int u = 0; u < 2; u++) {                        \
      auto ra = __builtin_amdgcn_permlane32_swap(Wp[4 * u + 0],            \
                                                 Wp[4 * u + 2], false,     \
                                                 false);                   \
      auto rb = __builtin_amdgcn_permlane32_swap(Wp[4 * u + 1],            \
                                                 Wp[4 * u + 3], false,     \
                                                 false);                   \
      uint4v fw;                                                           \
      fw[0] = ra[0];                                                       \
      fw[1] = rb[0];                                                       \
      fw[2] = ra[1];                                                       \
      fw[3] = rb[1];                                                       \
      pf[(st)*2 + u].u = fw;                                               \
    }                                                                      \
  }

  // denominator + PV MFMAs for kv-slots sA,sB (fragment sets pf[sA],pf[sB])
#define PVH(BUF, sA, sB)                                                   \
  {                                                                        \
    __builtin_amdgcn_s_setprio(1);                                         \
    od = MFMA32(onesu.s, pf[sA].s, od);                                    \
    od = MFMA32(onesu.s, pf[sB].s, od);                                    \
    _Pragma("unroll") for (int dt = 0; dt < 2; dt++) {                     \
      short8 vfa = *(const short8*)(lds0 + arf[sA] + (BUF)*16384 + 8192 +  \
                                    dt * 4096);                            \
      short8 vfb = *(const short8*)(lds0 + arf[sB] + (BUF)*16384 + 8192 +  \
                                    dt * 4096);                            \
      o[dt] = MFMA32(vfa, pf[sA].s, o[dt]);                                \
      o[dt] = MFMA32(vfb, pf[sB].s, o[dt]);                                \
    }                                                                      \
    __builtin_amdgcn_s_setprio(0);                                         \
  }

  STAGE(0, j0base);
  STAGE(1, j0base + 64);

  for (int t3 = 0; t3 < tps; t3 += 3) {
#pragma unroll
    for (int ib = 0; ib < 3; ib++) {  // buffer index = ib (static)
      const int tt = t3 + ib;
      // wait for tile tt's 2 loads only; tile tt+1's stay in flight across
      // the barrier (counted-vmcnt). Last iter drains fully.
      if (tt + 1 < tps) {
        asm volatile("s_waitcnt vmcnt(2)" ::: "memory");
      } else {
        asm volatile("s_waitcnt vmcnt(0)" ::: "memory");
      }
      __builtin_amdgcn_s_barrier();
      __builtin_amdgcn_sched_barrier(0);
      if (tt + 2 < tps) {
        STAGE((ib + 2) % 3, j0base + (tt + 2) * 64);
      }

      // QK both st slices; first MFMA of each chain uses zv as C (D != C)
      f32x16 s0, s1;
      __builtin_amdgcn_s_setprio(1);
      {
        short8 kf0 = *(const short8*)(lds0 + arf[0] + ib * 16384);
        short8 kf1 = *(const short8*)(lds0 + arf[0] + ib * 16384 + 4096);
        s0 = MFMA32(kf0, qf[0], zv);
        s1 = MFMA32(kf1, qf[0], zv);
      }
#pragma unroll
      for (int m = 1; m < 4; m++) {
        short8 kf0 = *(const short8*)(lds0 + arf[m] + ib * 16384);
        short8 kf1 = *(const short8*)(lds0 + arf[m] + ib * 16384 + 4096);
        s0 = MFMA32(kf0, qf[m], s0);
        s1 = MFMA32(kf1, qf[m], s1);
      }
      __builtin_amdgcn_s_setprio(0);

      B8 pf[4];
      SMPK1(s0, pf, 0);   // VALU: softmax st0 (overlaps s1's MFMA drain)
      PVH(ib, 0, 1);      // MFMA: den+PV for kv-slots 0,1
      SMPK1(s1, pf, 1);   // VALU: softmax st1 (overlaps PVH MFMA drain)
      PVH(ib, 2, 3);      // MFMA: den+PV for kv-slots 2,3
    }
  }

  // epilogue: denom = od[0] (all rows identical; row 0 lives in hs==0's r=0)
  if (hs == 0) LB[(size_t)split * 2 * L_ + (size_t)b * L_ + qrow] = od[0];

  ushort* Ob = OP + (size_t)split * 2 * 64 * L_;
#pragma unroll
  for (int dt = 0; dt < 2; dt++)
#pragma unroll
    for (int r = 0; r < 16; r++) {
      int dv = dt * 32 + (r & 3) + 8 * (r >> 2) + 4 * hs;
      Ob[(size_t)(b * 64 + dv) * L_ + qrow] = f2bf(o[dt][r]);
    }
}

// ---------------- combine splits (unrolled over NS) ----------------
// 8 output elements per thread. OP bf16, LB fp32.
template <int NS>
__global__ __launch_bounds__(256) void combine_kernel(
    const ushort* __restrict__ OP, const float* __restrict__ LB,
    float* __restrict__ out) {
  const size_t e = ((size_t)blockIdx.x * 256 + threadIdx.x) * 8;
  const int bdv = (int)(e / L_);
  const int b = bdv >> 6;
  const int q = (int)(e % L_);
  float os[8], ls[8];
#pragma unroll
  for (int i = 0; i < 8; i++) { os[i] = 0.f; ls[i] = 0.f; }
#pragma unroll
  for (int s = 0; s < NS; s++) {
    uint4v pv = *(const uint4v*)(OP + (size_t)s * 2 * 64 * L_ + e);
    const float* lp = LB + (size_t)s * 2 * L_ + (size_t)b * L_ + q;
    f32x4 l0 = *(const f32x4*)(lp);
    f32x4 l1 = *(const f32x4*)(lp + 4);
#pragma unroll
    for (int i = 0; i < 4; i++) {
      os[2 * i] += __uint_as_float(pv[i] << 16);
      os[2 * i + 1] += __uint_as_float(pv[i] & 0xFFFF0000u);
      ls[i] += l0[i];
      ls[4 + i] += l1[i];
    }
  }
  float r[8];
#pragma unroll
  for (int i = 0; i < 8; i++) r[i] = os[i] / ls[i];
  *(f32x4*)(out + e) = *(const f32x4*)&r[0];
  *(f32x4*)(out + e + 4) = *(const f32x4*)&r[4];
}

extern "C" void kernel_launch(void* const* d_in, const int* in_sizes, int n_in,
                              void* d_out, int out_size, void* d_ws, size_t ws_size,
                              hipStream_t stream) {
  const float* x = (const float*)d_in[0];
  const float* x_enc = (const float*)d_in[1];
  const float* Wq = (const float*)d_in[2];
  const float* bq = (const float*)d_in[3];
  const float* Wk = (const float*)d_in[4];
  const float* bk = (const float*)d_in[5];
  const float* Wv = (const float*)d_in[6];
  const float* bv = (const float*)d_in[7];
  float* out = (float*)d_out;

  ushort* Qb = (ushort*)d_ws;
  ushort* Kb = Qb + (size_t)2 * L_ * 64;
  ushort* Vb = Kb + (size_t)2 * L_ * 64;
  const size_t qkv_bytes = (size_t)3 * 2 * L_ * 64 * 2;  // 7,077,888

  // SPLIT = 16 fixed (ws fit confirmed rounds 11-21: OP bf16 ~37.7MB + LB)
  const int SPLIT = 16;
  ushort* OP = (ushort*)((char*)d_ws + qkv_bytes);
  float* LB = (float*)(OP + (size_t)SPLIT * 2 * 64 * L_);

  projm_kernel<<<dim3(576, 3), 64, 0, stream>>>(x, x_enc, Wq, bq, Wk, bk,
                                                Wv, bv, Qb, Kb, Vb);
  attn_kernel<<<72 * SPLIT, 512, 0, stream>>>(Qb, Kb, Vb, OP, LB, 144 / SPLIT);
  const int cgrid = (2 * 64 * L_ / 8) / 256;
  combine_kernel<16><<<cgrid, 256, 0, stream>>>(OP, LB, out);
}